// Round 1
// baseline (3147.494 us; speedup 1.0000x reference)
//
#include <hip/hip_runtime.h>
#include <math.h>

#define KNNK 20

__device__ __forceinline__ float lrelu(float v) { return v >= 0.f ? v : 0.2f * v; }

// ---------------- xx[b][n] = sum_c f[b][c][n]^2 ----------------
__global__ __launch_bounds__(256) void xx_kernel(const float* __restrict__ f, long bstride, int C,
                                                 float* __restrict__ xx) {
    int i = blockIdx.x * 256 + threadIdx.x;   // over B*N
    int b = i >> 11, n = i & 2047;
    const float* fb = f + (long)b * bstride;
    float s = 0.f;
    for (int c = 0; c < C; ++c) { float v = fb[c * 2048 + n]; s = fmaf(v, v, s); }
    xx[i] = s;
}

// ---------------- KNN: per 8-row strip, Gram + top-20 extraction ----------------
// grid (N/8, B), block 256. strip kept wholly in LDS (64 KB).
__global__ __launch_bounds__(256) void knn_kernel(const float* __restrict__ f, long bstride, int C,
                                                  const float* __restrict__ xx, int* __restrict__ idx_out) {
    __shared__ __align__(16) float lds[8 * 2048];   // phase2: first C*8 floats hold center block A; then full strip
    int b = blockIdx.y;
    int n0 = blockIdx.x * 8;
    int t = threadIdx.x;
    const float* fb = f + (long)b * bstride;

    // load center block A[c][j] = f[c][n0+j] into start of lds
    for (int e = t; e < C * 8; e += 256) {
        int c = e >> 3, j = e & 7;
        lds[e] = fb[c * 2048 + n0 + j];
    }
    __syncthreads();

    // per-thread: 8 rows x 8 cols (m = 8t..8t+7)
    float acc[8][8];
#pragma unroll
    for (int i = 0; i < 8; ++i)
#pragma unroll
        for (int j = 0; j < 8; ++j) acc[i][j] = 0.f;
    int m0 = t * 8;
    for (int c = 0; c < C; ++c) {
        float4 b0 = *(const float4*)(fb + c * 2048 + m0);
        float4 b1 = *(const float4*)(fb + c * 2048 + m0 + 4);
        float4 a0 = *(const float4*)(lds + c * 8);
        float4 a1 = *(const float4*)(lds + c * 8 + 4);
        float av[8] = {a0.x, a0.y, a0.z, a0.w, a1.x, a1.y, a1.z, a1.w};
        float bv[8] = {b0.x, b0.y, b0.z, b0.w, b1.x, b1.y, b1.z, b1.w};
#pragma unroll
        for (int i = 0; i < 8; ++i)
#pragma unroll
            for (int j = 0; j < 8; ++j) acc[i][j] = fmaf(av[i], bv[j], acc[i][j]);
    }
    float xn[8];
#pragma unroll
    for (int i = 0; i < 8; ++i) xn[i] = xx[b * 2048 + n0 + i];   // uniform scalar loads
    float4 x0 = *(const float4*)(xx + b * 2048 + m0);
    float4 x1 = *(const float4*)(xx + b * 2048 + m0 + 4);
    float xm[8] = {x0.x, x0.y, x0.z, x0.w, x1.x, x1.y, x1.z, x1.w};

    __syncthreads();   // everyone done reading A region before strip overwrites it
#pragma unroll
    for (int i = 0; i < 8; ++i) {
#pragma unroll
        for (int j = 0; j < 8; ++j)
            lds[i * 2048 + m0 + j] = (2.f * acc[i][j] - xn[i]) - xm[j];  // match JAX association order
    }
    __syncthreads();

    // selection: wave w handles rows 2w, 2w+1; 20-pass argmax extraction
    int wave = t >> 6, lane = t & 63;
    for (int rr = 0; rr < 2; ++rr) {
        int row = wave * 2 + rr;
        float* srow = lds + row * 2048;
        int* orow = idx_out + ((long)b * 2048 + n0 + row) * KNNK;
        for (int it = 0; it < KNNK; ++it) {
            float best = -INFINITY;
            int bi = 0x7fffffff;
            for (int i = lane; i < 2048; i += 64) {
                float v = srow[i];
                if (v > best) { best = v; bi = i; }      // '>' keeps smallest index on tie
            }
#pragma unroll
            for (int off = 32; off >= 1; off >>= 1) {
                float ov = __shfl_xor(best, off);
                int oi = __shfl_xor(bi, off);
                if (ov > best || (ov == best && oi < bi)) { best = ov; bi = oi; }  // JAX lowest-index tie-break
            }
            if (lane == 0) orow[it] = bi;
            if ((bi & 63) == lane) srow[bi] = -INFINITY;
            __threadfence_block();
        }
    }
}

// ---------------- P = Wa @ f, Q = (Wb - Wa) @ f, stored (B, N, 64) n-major ----------------
// W is (64, 2C) row-major. grid (N/64, B), block 256.
__global__ __launch_bounds__(256) void pq_kernel(const float* __restrict__ f, long bstride, int C,
                                                 const float* __restrict__ W, float* __restrict__ P,
                                                 float* __restrict__ Q) {
    __shared__ __align__(16) float wa[64 * 64];
    __shared__ __align__(16) float wq[64 * 64];
    __shared__ __align__(16) float X[64 * 64];
    int b = blockIdx.y, n0 = blockIdx.x * 64, t = threadIdx.x;
    const float* fb = f + (long)b * bstride;
    for (int e = t; e < C * 64; e += 256) {
        int k = e >> 6, c = e & 63;
        float a = W[c * 2 * C + k];
        float bv = W[c * 2 * C + C + k];
        wa[k * 64 + c] = a;
        wq[k * 64 + c] = bv - a;
    }
    for (int e = t; e < C * 64; e += 256) {
        int k = e >> 6, j = e & 63;
        X[e] = fb[k * 2048 + n0 + j];
    }
    __syncthreads();
    int cg = t >> 4, ng = t & 15;
    float accP[4][4] = {}, accQ[4][4] = {};
    for (int k = 0; k < C; ++k) {
        float4 a4 = *(const float4*)(wa + k * 64 + cg * 4);
        float4 q4 = *(const float4*)(wq + k * 64 + cg * 4);
        float4 x4 = *(const float4*)(X + k * 64 + ng * 4);
        float av[4] = {a4.x, a4.y, a4.z, a4.w};
        float qv[4] = {q4.x, q4.y, q4.z, q4.w};
        float xv[4] = {x4.x, x4.y, x4.z, x4.w};
#pragma unroll
        for (int i = 0; i < 4; ++i)
#pragma unroll
            for (int j = 0; j < 4; ++j) {
                accP[i][j] = fmaf(av[i], xv[j], accP[i][j]);
                accQ[i][j] = fmaf(qv[i], xv[j], accQ[i][j]);
            }
    }
#pragma unroll
    for (int j = 0; j < 4; ++j) {
        long n = n0 + ng * 4 + j;
        float4 pv = {accP[0][j], accP[1][j], accP[2][j], accP[3][j]};
        float4 qv = {accQ[0][j], accQ[1][j], accQ[2][j], accQ[3][j]};
        *(float4*)(P + ((long)b * 2048 + n) * 64 + cg * 4) = pv;
        *(float4*)(Q + ((long)b * 2048 + n) * 64 + cg * 4) = qv;
    }
}

// ---------------- EdgeConv layer-2 + max over k, fused (stages 1 & 2) ----------------
// h1[c,(n,k)] = lrelu(sa*(P[c,idx]+Q[c,n])+ta); out[c,n] = max_k lrelu(sb*(W2@h1)+tb)
// grid (N/8, B), block 256. T=8 points per workgroup -> 160 columns.
__global__ __launch_bounds__(256) void edge2_kernel(
    const float* __restrict__ P, const float* __restrict__ Q, const int* __restrict__ idx,
    const float* __restrict__ W2, const float* __restrict__ sa, const float* __restrict__ ta,
    const float* __restrict__ sb, const float* __restrict__ tb, float* __restrict__ out, int cofs) {
    __shared__ __align__(16) float h1[64 * 164];   // [cin][col], padded
    __shared__ __align__(16) float w2l[64 * 64];   // [cin][cout]
    __shared__ int idxl[160];
    int b = blockIdx.y, n0 = blockIdx.x * 8, t = threadIdx.x;
    if (t < 160) idxl[t] = idx[((long)b * 2048 + n0) * KNNK + t];
    for (int e = t; e < 4096; e += 256) { int co = e >> 6, ci = e & 63; w2l[ci * 64 + co] = W2[e]; }
    __syncthreads();
    for (int it = t; it < 2560; it += 256) {   // 160 cols x 16 channel-quads
        int col = it % 160, cg = it / 160;
        int p = col / 20;
        int j = idxl[col];
        int n = n0 + p;
        float4 pv = *(const float4*)(P + ((long)b * 2048 + j) * 64 + cg * 4);
        float4 qv = *(const float4*)(Q + ((long)b * 2048 + n) * 64 + cg * 4);
        float4 sv = *(const float4*)(sa + cg * 4);
        float4 tv = *(const float4*)(ta + cg * 4);
        h1[(cg * 4 + 0) * 164 + col] = lrelu(fmaf(sv.x, pv.x + qv.x, tv.x));
        h1[(cg * 4 + 1) * 164 + col] = lrelu(fmaf(sv.y, pv.y + qv.y, tv.y));
        h1[(cg * 4 + 2) * 164 + col] = lrelu(fmaf(sv.z, pv.z + qv.z, tv.z));
        h1[(cg * 4 + 3) * 164 + col] = lrelu(fmaf(sv.w, pv.w + qv.w, tv.w));
    }
    __syncthreads();
    int p = t & 7, co2 = t >> 3, c0 = co2 * 2;
    float acc0[20], acc1[20];
#pragma unroll
    for (int q = 0; q < 20; ++q) { acc0[q] = 0.f; acc1[q] = 0.f; }
#pragma unroll 4
    for (int k = 0; k < 64; ++k) {
        float2 w = *(const float2*)(w2l + k * 64 + c0);
        const float* hr = h1 + k * 164 + p * 20;
#pragma unroll
        for (int q = 0; q < 5; ++q) {
            float4 h4 = *(const float4*)(hr + q * 4);
            acc0[q * 4 + 0] = fmaf(w.x, h4.x, acc0[q * 4 + 0]);
            acc0[q * 4 + 1] = fmaf(w.x, h4.y, acc0[q * 4 + 1]);
            acc0[q * 4 + 2] = fmaf(w.x, h4.z, acc0[q * 4 + 2]);
            acc0[q * 4 + 3] = fmaf(w.x, h4.w, acc0[q * 4 + 3]);
            acc1[q * 4 + 0] = fmaf(w.y, h4.x, acc1[q * 4 + 0]);
            acc1[q * 4 + 1] = fmaf(w.y, h4.y, acc1[q * 4 + 1]);
            acc1[q * 4 + 2] = fmaf(w.y, h4.z, acc1[q * 4 + 2]);
            acc1[q * 4 + 3] = fmaf(w.y, h4.w, acc1[q * 4 + 3]);
        }
    }
    float s0 = sb[c0], t0v = tb[c0], s1 = sb[c0 + 1], t1v = tb[c0 + 1];
    float m0 = -INFINITY, m1 = -INFINITY;
#pragma unroll
    for (int q = 0; q < 20; ++q) {
        m0 = fmaxf(m0, lrelu(fmaf(s0, acc0[q], t0v)));
        m1 = fmaxf(m1, lrelu(fmaf(s1, acc1[q], t1v)));
    }
    out[(long)b * (192 * 2048) + (long)(cofs + c0) * 2048 + n0 + p] = m0;
    out[(long)b * (192 * 2048) + (long)(cofs + c0 + 1) * 2048 + n0 + p] = m1;
}

// ---------------- Stage 3: gather + affine + lrelu + max over k (no second conv) ----------------
// grid (N/4, B), block 256 = 64 channels x 4 points
__global__ __launch_bounds__(256) void edge1_kernel(const float* __restrict__ P, const float* __restrict__ Q,
                                                    const int* __restrict__ idx, const float* __restrict__ s,
                                                    const float* __restrict__ tt, float* __restrict__ out,
                                                    int cofs) {
    __shared__ int idxl[80];
    int b = blockIdx.y, n0 = blockIdx.x * 4, t = threadIdx.x;
    int c = t & 63, p = t >> 6;
    if (t < 80) idxl[t] = idx[((long)b * 2048 + n0) * KNNK + t];
    __syncthreads();
    float qv = Q[((long)b * 2048 + n0 + p) * 64 + c];
    float sc = s[c], tc = tt[c];
    float m = -INFINITY;
    for (int kk = 0; kk < KNNK; ++kk) {
        int j = idxl[p * KNNK + kk];
        float v = P[((long)b * 2048 + j) * 64 + c];
        m = fmaxf(m, lrelu(fmaf(sc, v + qv, tc)));
    }
    out[(long)b * (192 * 2048) + (long)(cofs + c) * 2048 + n0 + p] = m;
}

// ---------------- Generic head GEMM: out[b,c,n] = epilogue(W @ X) ----------------
// W (M,Kdim) with leading dim ldw; X (Kdim, 2048) per batch. Tile 64c x 128n, K-chunks of 32.
// If maxout != null: write per-(c, n-tile) running max of lrelu(s*acc+t) instead of storing.
__global__ __launch_bounds__(256) void gemm_kernel(
    const float* __restrict__ W, int ldw, int Kdim, const float* __restrict__ X, long xbstride,
    const float* __restrict__ s, const float* __restrict__ tvec, const float* __restrict__ bias, int M,
    float* __restrict__ out, long obstride, float* __restrict__ maxout) {
    __shared__ __align__(16) float wl[32 * 68];
    __shared__ __align__(16) float xl[32 * 132];
    int b = blockIdx.z, ct = blockIdx.x * 64, nt = blockIdx.y * 128, t = threadIdx.x;
    const float* Xb = X + (long)b * xbstride;
    int cg = t >> 4, ng = t & 15;
    float acc[4][8];
#pragma unroll
    for (int i = 0; i < 4; ++i)
#pragma unroll
        for (int j = 0; j < 8; ++j) acc[i][j] = 0.f;
    for (int k0 = 0; k0 < Kdim; k0 += 32) {
        __syncthreads();
        for (int e = t; e < 2048; e += 256) {
            int c = e >> 5, k = e & 31;
            wl[k * 68 + c] = W[(long)(ct + c) * ldw + k0 + k];
        }
        for (int e = t; e < 4096; e += 256) {
            int k = e >> 7, j = e & 127;
            xl[k * 132 + j] = Xb[(long)(k0 + k) * 2048 + nt + j];
        }
        __syncthreads();
#pragma unroll 8
        for (int k = 0; k < 32; ++k) {
            float4 w4 = *(const float4*)(wl + k * 68 + cg * 4);
            float4 xa = *(const float4*)(xl + k * 132 + ng * 8);
            float4 xb = *(const float4*)(xl + k * 132 + ng * 8 + 4);
            float wv[4] = {w4.x, w4.y, w4.z, w4.w};
            float xv[8] = {xa.x, xa.y, xa.z, xa.w, xb.x, xb.y, xb.z, xb.w};
#pragma unroll
            for (int i = 0; i < 4; ++i)
#pragma unroll
                for (int j = 0; j < 8; ++j) acc[i][j] = fmaf(wv[i], xv[j], acc[i][j]);
        }
    }
    if (maxout) {
        __syncthreads();
        float* scr = xl;   // reuse
#pragma unroll
        for (int i = 0; i < 4; ++i) {
            int c = ct + cg * 4 + i;
            float sv = s[c], tv = tvec[c];
            float m = -INFINITY;
#pragma unroll
            for (int j = 0; j < 8; ++j) m = fmaxf(m, lrelu(fmaf(sv, acc[i][j], tv)));
            scr[(cg * 4 + i) * 16 + ng] = m;
        }
        __syncthreads();
        if (t < 64) {
            float m = scr[t * 16];
            for (int j = 1; j < 16; ++j) m = fmaxf(m, scr[t * 16 + j]);
            maxout[((long)b * M + ct + t) * 16 + blockIdx.y] = m;
        }
    } else {
#pragma unroll
        for (int i = 0; i < 4; ++i) {
            int c = ct + cg * 4 + i;
            float bv = bias ? bias[b * M + c] : 0.f;
            float sv = s[c], tv = tvec[c];
            float4 o0, o1;
            o0.x = lrelu(fmaf(sv, acc[i][0] + bv, tv));
            o0.y = lrelu(fmaf(sv, acc[i][1] + bv, tv));
            o0.z = lrelu(fmaf(sv, acc[i][2] + bv, tv));
            o0.w = lrelu(fmaf(sv, acc[i][3] + bv, tv));
            o1.x = lrelu(fmaf(sv, acc[i][4] + bv, tv));
            o1.y = lrelu(fmaf(sv, acc[i][5] + bv, tv));
            o1.z = lrelu(fmaf(sv, acc[i][6] + bv, tv));
            o1.w = lrelu(fmaf(sv, acc[i][7] + bv, tv));
            float* op = out + (long)b * obstride + (long)c * 2048 + nt + ng * 8;
            *(float4*)op = o0;
            *(float4*)(op + 4) = o1;
        }
    }
}

// ---------------- finalize g = max over the 16 n-tile partials ----------------
__global__ __launch_bounds__(256) void gmax_final(const float* __restrict__ ep, float* __restrict__ g) {
    int i = blockIdx.x * 256 + threadIdx.x;   // < 16*1024
    float m = ep[i * 16];
    for (int j = 1; j < 16; ++j) m = fmaxf(m, ep[i * 16 + j]);
    g[i] = m;
}

// ---------------- bias7[b][co] = w7[co, :1024] @ g[b] ----------------
__global__ __launch_bounds__(64) void bias7_kernel(const float* __restrict__ w7, const float* __restrict__ g,
                                                   float* __restrict__ bias7) {
    int o = blockIdx.x;            // b*512 + co
    int b = o >> 9, co = o & 511;
    int lane = threadIdx.x;
    float acc = 0.f;
    for (int j = lane; j < 1024; j += 64) acc = fmaf(w7[(long)co * 1216 + j], g[b * 1024 + j], acc);
#pragma unroll
    for (int off = 32; off >= 1; off >>= 1) acc += __shfl_xor(acc, off);
    if (lane == 0) bias7[o] = acc;
}

// ---------------- y[b][n] = sigmoid(w9 @ h8[:, n]) ----------------
__global__ __launch_bounds__(256) void w9_kernel(const float* __restrict__ w9, const float* __restrict__ h8,
                                                 float* __restrict__ out) {
    int i = blockIdx.x * 256 + threadIdx.x;   // over B*N
    int b = i >> 11, n = i & 2047;
    const float* hb = h8 + (long)b * 256 * 2048 + n;
    float acc = 0.f;
    for (int c = 0; c < 256; ++c) acc = fmaf(w9[c], hb[c * 2048], acc);
    out[i] = 1.f / (1.f + expf(-acc));
}

extern "C" void kernel_launch(void* const* d_in, const int* in_sizes, int n_in,
                              void* d_out, int out_size, void* d_ws, size_t ws_size,
                              hipStream_t stream) {
    (void)in_sizes; (void)n_in; (void)out_size; (void)ws_size;
    const float* x  = (const float*)d_in[0];
    const float* w1 = (const float*)d_in[1];
    const float* w2 = (const float*)d_in[2];
    const float* w3 = (const float*)d_in[3];
    const float* w4 = (const float*)d_in[4];
    const float* w5 = (const float*)d_in[5];
    const float* w6 = (const float*)d_in[6];
    const float* w7 = (const float*)d_in[7];
    const float* w8 = (const float*)d_in[8];
    const float* w9 = (const float*)d_in[9];
    const float* s1 = (const float*)d_in[10]; const float* t1 = (const float*)d_in[11];
    const float* s2 = (const float*)d_in[12]; const float* t2 = (const float*)d_in[13];
    const float* s3 = (const float*)d_in[14]; const float* t3 = (const float*)d_in[15];
    const float* s4 = (const float*)d_in[16]; const float* t4 = (const float*)d_in[17];
    const float* s5 = (const float*)d_in[18]; const float* t5 = (const float*)d_in[19];
    const float* s6 = (const float*)d_in[20]; const float* t6 = (const float*)d_in[21];
    const float* s7 = (const float*)d_in[22]; const float* t7 = (const float*)d_in[23];
    const float* s8 = (const float*)d_in[24]; const float* t8 = (const float*)d_in[25];

    // workspace partition (floats)
    float* cat = (float*)d_ws;                          // 16*192*2048
    float* xxb = cat + (long)16 * 192 * 2048;           // 16*2048
    int*   idxb = (int*)(xxb + 16 * 2048);              // 16*2048*20 ints
    float* P  = (float*)(idxb + (long)16 * 2048 * 20);  // 16*2048*64
    float* Q  = P + (long)16 * 2048 * 64;               // 16*2048*64
    float* ep = Q + (long)16 * 2048 * 64;               // 16*1024*16
    float* g  = ep + 16 * 1024 * 16;                    // 16*1024
    float* b7 = g + 16 * 1024;                          // 16*512
    float* h7 = b7 + 16 * 512;                          // 16*512*2048
    float* h8 = h7 + (long)16 * 512 * 2048;             // 16*256*2048

    dim3 blk(256);
    long catstride = 192 * 2048;

    // ---- stage 1 (C=2) ----
    xx_kernel<<<128, blk, 0, stream>>>(x, 2 * 2048, 2, xxb);
    knn_kernel<<<dim3(256, 16), blk, 0, stream>>>(x, 2 * 2048, 2, xxb, idxb);
    pq_kernel<<<dim3(32, 16), blk, 0, stream>>>(x, 2 * 2048, 2, w1, P, Q);
    edge2_kernel<<<dim3(256, 16), blk, 0, stream>>>(P, Q, idxb, w2, s1, t1, s2, t2, cat, 0);
    // ---- stage 2 (C=64 on x1) ----
    xx_kernel<<<128, blk, 0, stream>>>(cat, catstride, 64, xxb);
    knn_kernel<<<dim3(256, 16), blk, 0, stream>>>(cat, catstride, 64, xxb, idxb);
    pq_kernel<<<dim3(32, 16), blk, 0, stream>>>(cat, catstride, 64, w3, P, Q);
    edge2_kernel<<<dim3(256, 16), blk, 0, stream>>>(P, Q, idxb, w4, s3, t3, s4, t4, cat, 64);
    // ---- stage 3 (C=64 on x2) ----
    xx_kernel<<<128, blk, 0, stream>>>(cat + 64 * 2048, catstride, 64, xxb);
    knn_kernel<<<dim3(256, 16), blk, 0, stream>>>(cat + 64 * 2048, catstride, 64, xxb, idxb);
    pq_kernel<<<dim3(32, 16), blk, 0, stream>>>(cat + 64 * 2048, catstride, 64, w5, P, Q);
    edge1_kernel<<<dim3(512, 16), blk, 0, stream>>>(P, Q, idxb, s5, t5, cat, 128);
    // ---- head ----
    // e = lrelu(s6*(w6@cat)+t6), g = max_n e   (fused partial-max, never materialized)
    gemm_kernel<<<dim3(16, 16, 16), blk, 0, stream>>>(w6, 192, 192, cat, catstride, s6, t6, nullptr, 1024,
                                                      nullptr, 0, ep);
    gmax_final<<<64, blk, 0, stream>>>(ep, g);
    // w7 @ [g; cat] = bias7 (w7a@g) + w7b@cat
    bias7_kernel<<<dim3(16 * 512), dim3(64), 0, stream>>>(w7, g, b7);
    gemm_kernel<<<dim3(8, 16, 16), blk, 0, stream>>>(w7 + 1024, 1216, 192, cat, catstride, s7, t7, b7, 512,
                                                     h7, (long)512 * 2048, nullptr);
    gemm_kernel<<<dim3(4, 16, 16), blk, 0, stream>>>(w8, 512, 512, h7, (long)512 * 2048, s8, t8, nullptr, 256,
                                                     h8, (long)256 * 2048, nullptr);
    w9_kernel<<<128, blk, 0, stream>>>(w9, h8, (float*)d_out);
}

// Round 2
// 1506.038 us; speedup vs baseline: 2.0899x; 2.0899x over previous
//
#include <hip/hip_runtime.h>
#include <math.h>

#define KNNK 20

__device__ __forceinline__ float lrelu(float v) { return v >= 0.f ? v : 0.2f * v; }

// ---------------- xx[b][n] = sum_c f[b][c][n]^2 ----------------
__global__ __launch_bounds__(256) void xx_kernel(const float* __restrict__ f, long bstride, int C,
                                                 float* __restrict__ xx) {
    int i = blockIdx.x * 256 + threadIdx.x;   // over B*N
    int b = i >> 11, n = i & 2047;
    const float* fb = f + (long)b * bstride;
    float s = 0.f;
    for (int c = 0; c < C; ++c) { float v = fb[c * 2048 + n]; s = fmaf(v, v, s); }
    xx[i] = s;
}

// ---------------- KNN: per 8-row strip, Gram + register-resident top-20 ----------------
// grid (N/8, B), block 512 (8 waves, 1 row per wave). 64 KB LDS -> 2 blocks/CU = 16 waves/CU.
__global__ __launch_bounds__(512, 4) void knn_kernel(const float* __restrict__ f, long bstride, int C,
                                                     const float* __restrict__ xx, int* __restrict__ idx_out) {
    __shared__ __align__(16) float lds[8 * 2048];   // phase1: first C*8 floats = center block A; phase2: 8x2048 distances
    int b = blockIdx.y;
    int n0 = blockIdx.x * 8;
    int t = threadIdx.x;
    const float* fb = f + (long)b * bstride;

    // stage center block A[c][j] = f[c][n0+j]
    for (int e = t; e < C * 8; e += 512) {
        int c = e >> 3, j = e & 7;
        lds[e] = fb[c * 2048 + n0 + j];
    }
    __syncthreads();

    // Gram: thread t owns cols m0..m0+3, all 8 rows. Accumulation order over c identical
    // to round-0 kernel -> bit-identical distances.
    float acc[8][4];
#pragma unroll
    for (int i = 0; i < 8; ++i)
#pragma unroll
        for (int j = 0; j < 4; ++j) acc[i][j] = 0.f;
    int m0 = t * 4;
    for (int c = 0; c < C; ++c) {
        float4 b4 = *(const float4*)(fb + c * 2048 + m0);
        float bv[4] = {b4.x, b4.y, b4.z, b4.w};
        float4 a0 = *(const float4*)(lds + c * 8);
        float4 a1 = *(const float4*)(lds + c * 8 + 4);
        float av[8] = {a0.x, a0.y, a0.z, a0.w, a1.x, a1.y, a1.z, a1.w};
#pragma unroll
        for (int i = 0; i < 8; ++i)
#pragma unroll
            for (int j = 0; j < 4; ++j) acc[i][j] = fmaf(av[i], bv[j], acc[i][j]);
    }
    float xn[8];
#pragma unroll
    for (int i = 0; i < 8; ++i) xn[i] = xx[b * 2048 + n0 + i];   // wave-uniform scalar loads
    float4 xm4 = *(const float4*)(xx + b * 2048 + m0);
    float xm[4] = {xm4.x, xm4.y, xm4.z, xm4.w};

    __syncthreads();   // A region fully consumed before distance rows overwrite it
#pragma unroll
    for (int i = 0; i < 8; ++i) {
        float4 o;
        o.x = (2.f * acc[i][0] - xn[i]) - xm[0];   // match JAX association order
        o.y = (2.f * acc[i][1] - xn[i]) - xm[1];
        o.z = (2.f * acc[i][2] - xn[i]) - xm[2];
        o.w = (2.f * acc[i][3] - xn[i]) - xm[3];
        *(float4*)(lds + i * 2048 + m0) = o;       // contiguous b128, conflict-free
    }
    __syncthreads();

    // ---- selection: wave w extracts top-20 of row w, register-resident ----
    int wave = t >> 6, lane = t & 63;
    const float* srow = lds + wave * 2048;
    float v[32];
#pragma unroll
    for (int j = 0; j < 32; ++j) v[j] = srow[lane + 64 * j];   // global index i = lane + 64*j

    // per-lane top-2 (strict '>' ascending keeps earliest index on ties)
    float b1 = -INFINITY, b2 = -INFINITY;
    int j1 = 0, j2 = 0;
#pragma unroll
    for (int j = 0; j < 32; ++j) {
        float vv = v[j];
        bool c1 = vv > b1;
        bool c2 = vv > b2;
        b2 = c1 ? b1 : (c2 ? vv : b2);
        j2 = c1 ? j1 : (c2 ? j : j2);
        b1 = c1 ? vv : b1;
        j1 = c1 ? j : j1;
    }

    unsigned rem = 0u;   // removed-element bitmask over this lane's 32 slots
    int win_i = 0;
    for (int pass = 0; pass < KNNK; ++pass) {
        // value-only butterfly max over the 64 lane-bests
        float m = b1;
#pragma unroll
        for (int off = 32; off >= 1; off >>= 1) m = fmaxf(m, __shfl_xor(m, off));
        unsigned long long tied = __ballot(b1 == m);
        int iw;
        if (__popcll(tied) == 1) {
            int owner = __ffsll(tied) - 1;
            iw = owner + (__shfl(j1, owner) << 6);
        } else {
            // exact-tie slow path: lowest global index wins (JAX tie-break)
            int ic = (b1 == m) ? (lane + (j1 << 6)) : 0x7fffffff;
#pragma unroll
            for (int off = 32; off >= 1; off >>= 1) ic = min(ic, __shfl_xor(ic, off));
            iw = ic;
        }
        if (lane == pass) win_i = iw;
        // owner pops its best
        if (lane == (iw & 63)) {
            rem |= 1u << j1;
            b1 = b2; j1 = j2;
            b2 = -INFINITY; j2 = 0;
        }
        // lazy refill: only when some lane's b1 went invalid (3rd+ winner from that lane)
        if (__any(b1 == -INFINITY)) {
            bool need = (b1 == -INFINITY);
            float nb1 = -INFINITY, nb2 = -INFINITY;
            int nj1 = 0, nj2 = 0;
#pragma unroll
            for (int j = 0; j < 32; ++j) {
                float vv = ((rem >> j) & 1u) ? -INFINITY : v[j];
                bool c1 = vv > nb1;
                bool c2 = vv > nb2;
                nb2 = c1 ? nb1 : (c2 ? vv : nb2);
                nj2 = c1 ? nj1 : (c2 ? j : nj2);
                nb1 = c1 ? vv : nb1;
                nj1 = c1 ? j : nj1;
            }
            if (need) { b1 = nb1; j1 = nj1; b2 = nb2; j2 = nj2; }
        }
    }
    int* orow = idx_out + ((long)b * 2048 + n0 + wave) * KNNK;
    if (lane < KNNK) orow[lane] = win_i;
}

// ---------------- P = Wa @ f, Q = (Wb - Wa) @ f, stored (B, N, 64) n-major ----------------
// W is (64, 2C) row-major. grid (N/64, B), block 256.
__global__ __launch_bounds__(256) void pq_kernel(const float* __restrict__ f, long bstride, int C,
                                                 const float* __restrict__ W, float* __restrict__ P,
                                                 float* __restrict__ Q) {
    __shared__ __align__(16) float wa[64 * 64];
    __shared__ __align__(16) float wq[64 * 64];
    __shared__ __align__(16) float X[64 * 64];
    int b = blockIdx.y, n0 = blockIdx.x * 64, t = threadIdx.x;
    const float* fb = f + (long)b * bstride;
    for (int e = t; e < C * 64; e += 256) {
        int k = e >> 6, c = e & 63;
        float a = W[c * 2 * C + k];
        float bv = W[c * 2 * C + C + k];
        wa[k * 64 + c] = a;
        wq[k * 64 + c] = bv - a;
    }
    for (int e = t; e < C * 64; e += 256) {
        int k = e >> 6, j = e & 63;
        X[e] = fb[k * 2048 + n0 + j];
    }
    __syncthreads();
    int cg = t >> 4, ng = t & 15;
    float accP[4][4] = {}, accQ[4][4] = {};
    for (int k = 0; k < C; ++k) {
        float4 a4 = *(const float4*)(wa + k * 64 + cg * 4);
        float4 q4 = *(const float4*)(wq + k * 64 + cg * 4);
        float4 x4 = *(const float4*)(X + k * 64 + ng * 4);
        float av[4] = {a4.x, a4.y, a4.z, a4.w};
        float qv[4] = {q4.x, q4.y, q4.z, q4.w};
        float xv[4] = {x4.x, x4.y, x4.z, x4.w};
#pragma unroll
        for (int i = 0; i < 4; ++i)
#pragma unroll
            for (int j = 0; j < 4; ++j) {
                accP[i][j] = fmaf(av[i], xv[j], accP[i][j]);
                accQ[i][j] = fmaf(qv[i], xv[j], accQ[i][j]);
            }
    }
#pragma unroll
    for (int j = 0; j < 4; ++j) {
        long n = n0 + ng * 4 + j;
        float4 pv = {accP[0][j], accP[1][j], accP[2][j], accP[3][j]};
        float4 qv = {accQ[0][j], accQ[1][j], accQ[2][j], accQ[3][j]};
        *(float4*)(P + ((long)b * 2048 + n) * 64 + cg * 4) = pv;
        *(float4*)(Q + ((long)b * 2048 + n) * 64 + cg * 4) = qv;
    }
}

// ---------------- EdgeConv layer-2 + max over k, fused (stages 1 & 2) ----------------
__global__ __launch_bounds__(256) void edge2_kernel(
    const float* __restrict__ P, const float* __restrict__ Q, const int* __restrict__ idx,
    const float* __restrict__ W2, const float* __restrict__ sa, const float* __restrict__ ta,
    const float* __restrict__ sb, const float* __restrict__ tb, float* __restrict__ out, int cofs) {
    __shared__ __align__(16) float h1[64 * 164];   // [cin][col], padded
    __shared__ __align__(16) float w2l[64 * 64];   // [cin][cout]
    __shared__ int idxl[160];
    int b = blockIdx.y, n0 = blockIdx.x * 8, t = threadIdx.x;
    if (t < 160) idxl[t] = idx[((long)b * 2048 + n0) * KNNK + t];
    for (int e = t; e < 4096; e += 256) { int co = e >> 6, ci = e & 63; w2l[ci * 64 + co] = W2[e]; }
    __syncthreads();
    for (int it = t; it < 2560; it += 256) {   // 160 cols x 16 channel-quads
        int col = it % 160, cg = it / 160;
        int p = col / 20;
        int j = idxl[col];
        int n = n0 + p;
        float4 pv = *(const float4*)(P + ((long)b * 2048 + j) * 64 + cg * 4);
        float4 qv = *(const float4*)(Q + ((long)b * 2048 + n) * 64 + cg * 4);
        float4 sv = *(const float4*)(sa + cg * 4);
        float4 tv = *(const float4*)(ta + cg * 4);
        h1[(cg * 4 + 0) * 164 + col] = lrelu(fmaf(sv.x, pv.x + qv.x, tv.x));
        h1[(cg * 4 + 1) * 164 + col] = lrelu(fmaf(sv.y, pv.y + qv.y, tv.y));
        h1[(cg * 4 + 2) * 164 + col] = lrelu(fmaf(sv.z, pv.z + qv.z, tv.z));
        h1[(cg * 4 + 3) * 164 + col] = lrelu(fmaf(sv.w, pv.w + qv.w, tv.w));
    }
    __syncthreads();
    int p = t & 7, co2 = t >> 3, c0 = co2 * 2;
    float acc0[20], acc1[20];
#pragma unroll
    for (int q = 0; q < 20; ++q) { acc0[q] = 0.f; acc1[q] = 0.f; }
#pragma unroll 4
    for (int k = 0; k < 64; ++k) {
        float2 w = *(const float2*)(w2l + k * 64 + c0);
        const float* hr = h1 + k * 164 + p * 20;
#pragma unroll
        for (int q = 0; q < 5; ++q) {
            float4 h4 = *(const float4*)(hr + q * 4);
            acc0[q * 4 + 0] = fmaf(w.x, h4.x, acc0[q * 4 + 0]);
            acc0[q * 4 + 1] = fmaf(w.x, h4.y, acc0[q * 4 + 1]);
            acc0[q * 4 + 2] = fmaf(w.x, h4.z, acc0[q * 4 + 2]);
            acc0[q * 4 + 3] = fmaf(w.x, h4.w, acc0[q * 4 + 3]);
            acc1[q * 4 + 0] = fmaf(w.y, h4.x, acc1[q * 4 + 0]);
            acc1[q * 4 + 1] = fmaf(w.y, h4.y, acc1[q * 4 + 1]);
            acc1[q * 4 + 2] = fmaf(w.y, h4.z, acc1[q * 4 + 2]);
            acc1[q * 4 + 3] = fmaf(w.y, h4.w, acc1[q * 4 + 3]);
        }
    }
    float s0 = sb[c0], t0v = tb[c0], s1 = sb[c0 + 1], t1v = tb[c0 + 1];
    float m0 = -INFINITY, m1 = -INFINITY;
#pragma unroll
    for (int q = 0; q < 20; ++q) {
        m0 = fmaxf(m0, lrelu(fmaf(s0, acc0[q], t0v)));
        m1 = fmaxf(m1, lrelu(fmaf(s1, acc1[q], t1v)));
    }
    out[(long)b * (192 * 2048) + (long)(cofs + c0) * 2048 + n0 + p] = m0;
    out[(long)b * (192 * 2048) + (long)(cofs + c0 + 1) * 2048 + n0 + p] = m1;
}

// ---------------- Stage 3: gather + affine + lrelu + max over k ----------------
__global__ __launch_bounds__(256) void edge1_kernel(const float* __restrict__ P, const float* __restrict__ Q,
                                                    const int* __restrict__ idx, const float* __restrict__ s,
                                                    const float* __restrict__ tt, float* __restrict__ out,
                                                    int cofs) {
    __shared__ int idxl[80];
    int b = blockIdx.y, n0 = blockIdx.x * 4, t = threadIdx.x;
    int c = t & 63, p = t >> 6;
    if (t < 80) idxl[t] = idx[((long)b * 2048 + n0) * KNNK + t];
    __syncthreads();
    float qv = Q[((long)b * 2048 + n0 + p) * 64 + c];
    float sc = s[c], tc = tt[c];
    float m = -INFINITY;
    for (int kk = 0; kk < KNNK; ++kk) {
        int j = idxl[p * KNNK + kk];
        float v = P[((long)b * 2048 + j) * 64 + c];
        m = fmaxf(m, lrelu(fmaf(sc, v + qv, tc)));
    }
    out[(long)b * (192 * 2048) + (long)(cofs + c) * 2048 + n0 + p] = m;
}

// ---------------- Generic head GEMM ----------------
__global__ __launch_bounds__(256) void gemm_kernel(
    const float* __restrict__ W, int ldw, int Kdim, const float* __restrict__ X, long xbstride,
    const float* __restrict__ s, const float* __restrict__ tvec, const float* __restrict__ bias, int M,
    float* __restrict__ out, long obstride, float* __restrict__ maxout) {
    __shared__ __align__(16) float wl[32 * 68];
    __shared__ __align__(16) float xl[32 * 132];
    int b = blockIdx.z, ct = blockIdx.x * 64, nt = blockIdx.y * 128, t = threadIdx.x;
    const float* Xb = X + (long)b * xbstride;
    int cg = t >> 4, ng = t & 15;
    float acc[4][8];
#pragma unroll
    for (int i = 0; i < 4; ++i)
#pragma unroll
        for (int j = 0; j < 8; ++j) acc[i][j] = 0.f;
    for (int k0 = 0; k0 < Kdim; k0 += 32) {
        __syncthreads();
        for (int e = t; e < 2048; e += 256) {
            int c = e >> 5, k = e & 31;
            wl[k * 68 + c] = W[(long)(ct + c) * ldw + k0 + k];
        }
        for (int e = t; e < 4096; e += 256) {
            int k = e >> 7, j = e & 127;
            xl[k * 132 + j] = Xb[(long)(k0 + k) * 2048 + nt + j];
        }
        __syncthreads();
#pragma unroll 8
        for (int k = 0; k < 32; ++k) {
            float4 w4 = *(const float4*)(wl + k * 68 + cg * 4);
            float4 xa = *(const float4*)(xl + k * 132 + ng * 8);
            float4 xb = *(const float4*)(xl + k * 132 + ng * 8 + 4);
            float wv[4] = {w4.x, w4.y, w4.z, w4.w};
            float xv[8] = {xa.x, xa.y, xa.z, xa.w, xb.x, xb.y, xb.z, xb.w};
#pragma unroll
            for (int i = 0; i < 4; ++i)
#pragma unroll
                for (int j = 0; j < 8; ++j) acc[i][j] = fmaf(wv[i], xv[j], acc[i][j]);
        }
    }
    if (maxout) {
        __syncthreads();
        float* scr = xl;   // reuse
#pragma unroll
        for (int i = 0; i < 4; ++i) {
            int c = ct + cg * 4 + i;
            float sv = s[c], tv = tvec[c];
            float m = -INFINITY;
#pragma unroll
            for (int j = 0; j < 8; ++j) m = fmaxf(m, lrelu(fmaf(sv, acc[i][j], tv)));
            scr[(cg * 4 + i) * 16 + ng] = m;
        }
        __syncthreads();
        if (t < 64) {
            float m = scr[t * 16];
            for (int j = 1; j < 16; ++j) m = fmaxf(m, scr[t * 16 + j]);
            maxout[((long)b * M + ct + t) * 16 + blockIdx.y] = m;
        }
    } else {
#pragma unroll
        for (int i = 0; i < 4; ++i) {
            int c = ct + cg * 4 + i;
            float bv = bias ? bias[b * M + c] : 0.f;
            float sv = s[c], tv = tvec[c];
            float4 o0, o1;
            o0.x = lrelu(fmaf(sv, acc[i][0] + bv, tv));
            o0.y = lrelu(fmaf(sv, acc[i][1] + bv, tv));
            o0.z = lrelu(fmaf(sv, acc[i][2] + bv, tv));
            o0.w = lrelu(fmaf(sv, acc[i][3] + bv, tv));
            o1.x = lrelu(fmaf(sv, acc[i][4] + bv, tv));
            o1.y = lrelu(fmaf(sv, acc[i][5] + bv, tv));
            o1.z = lrelu(fmaf(sv, acc[i][6] + bv, tv));
            o1.w = lrelu(fmaf(sv, acc[i][7] + bv, tv));
            float* op = out + (long)b * obstride + (long)c * 2048 + nt + ng * 8;
            *(float4*)op = o0;
            *(float4*)(op + 4) = o1;
        }
    }
}

// ---------------- finalize g = max over the 16 n-tile partials ----------------
__global__ __launch_bounds__(256) void gmax_final(const float* __restrict__ ep, float* __restrict__ g) {
    int i = blockIdx.x * 256 + threadIdx.x;   // < 16*1024
    float m = ep[i * 16];
    for (int j = 1; j < 16; ++j) m = fmaxf(m, ep[i * 16 + j]);
    g[i] = m;
}

// ---------------- bias7[b][co] = w7[co, :1024] @ g[b] ----------------
__global__ __launch_bounds__(64) void bias7_kernel(const float* __restrict__ w7, const float* __restrict__ g,
                                                   float* __restrict__ bias7) {
    int o = blockIdx.x;            // b*512 + co
    int b = o >> 9, co = o & 511;
    int lane = threadIdx.x;
    float acc = 0.f;
    for (int j = lane; j < 1024; j += 64) acc = fmaf(w7[(long)co * 1216 + j], g[b * 1024 + j], acc);
#pragma unroll
    for (int off = 32; off >= 1; off >>= 1) acc += __shfl_xor(acc, off);
    if (lane == 0) bias7[o] = acc;
}

// ---------------- y[b][n] = sigmoid(w9 @ h8[:, n]) ----------------
__global__ __launch_bounds__(256) void w9_kernel(const float* __restrict__ w9, const float* __restrict__ h8,
                                                 float* __restrict__ out) {
    int i = blockIdx.x * 256 + threadIdx.x;   // over B*N
    int b = i >> 11, n = i & 2047;
    const float* hb = h8 + (long)b * 256 * 2048 + n;
    float acc = 0.f;
    for (int c = 0; c < 256; ++c) acc = fmaf(w9[c], hb[c * 2048], acc);
    out[i] = 1.f / (1.f + expf(-acc));
}

extern "C" void kernel_launch(void* const* d_in, const int* in_sizes, int n_in,
                              void* d_out, int out_size, void* d_ws, size_t ws_size,
                              hipStream_t stream) {
    (void)in_sizes; (void)n_in; (void)out_size; (void)ws_size;
    const float* x  = (const float*)d_in[0];
    const float* w1 = (const float*)d_in[1];
    const float* w2 = (const float*)d_in[2];
    const float* w3 = (const float*)d_in[3];
    const float* w4 = (const float*)d_in[4];
    const float* w5 = (const float*)d_in[5];
    const float* w6 = (const float*)d_in[6];
    const float* w7 = (const float*)d_in[7];
    const float* w8 = (const float*)d_in[8];
    const float* w9 = (const float*)d_in[9];
    const float* s1 = (const float*)d_in[10]; const float* t1 = (const float*)d_in[11];
    const float* s2 = (const float*)d_in[12]; const float* t2 = (const float*)d_in[13];
    const float* s3 = (const float*)d_in[14]; const float* t3 = (const float*)d_in[15];
    const float* s4 = (const float*)d_in[16]; const float* t4 = (const float*)d_in[17];
    const float* s5 = (const float*)d_in[18]; const float* t5 = (const float*)d_in[19];
    const float* s6 = (const float*)d_in[20]; const float* t6 = (const float*)d_in[21];
    const float* s7 = (const float*)d_in[22]; const float* t7 = (const float*)d_in[23];
    const float* s8 = (const float*)d_in[24]; const float* t8 = (const float*)d_in[25];

    // workspace partition (floats)
    float* cat = (float*)d_ws;                          // 16*192*2048
    float* xxb = cat + (long)16 * 192 * 2048;           // 16*2048
    int*   idxb = (int*)(xxb + 16 * 2048);              // 16*2048*20 ints
    float* P  = (float*)(idxb + (long)16 * 2048 * 20);  // 16*2048*64
    float* Q  = P + (long)16 * 2048 * 64;               // 16*2048*64
    float* ep = Q + (long)16 * 2048 * 64;               // 16*1024*16
    float* g  = ep + 16 * 1024 * 16;                    // 16*1024
    float* b7 = g + 16 * 1024;                          // 16*512
    float* h7 = b7 + 16 * 512;                          // 16*512*2048
    float* h8 = h7 + (long)16 * 512 * 2048;             // 16*256*2048

    dim3 blk(256);
    dim3 blk512(512);
    long catstride = 192 * 2048;

    // ---- stage 1 (C=2) ----
    xx_kernel<<<128, blk, 0, stream>>>(x, 2 * 2048, 2, xxb);
    knn_kernel<<<dim3(256, 16), blk512, 0, stream>>>(x, 2 * 2048, 2, xxb, idxb);
    pq_kernel<<<dim3(32, 16), blk, 0, stream>>>(x, 2 * 2048, 2, w1, P, Q);
    edge2_kernel<<<dim3(256, 16), blk, 0, stream>>>(P, Q, idxb, w2, s1, t1, s2, t2, cat, 0);
    // ---- stage 2 (C=64 on x1) ----
    xx_kernel<<<128, blk, 0, stream>>>(cat, catstride, 64, xxb);
    knn_kernel<<<dim3(256, 16), blk512, 0, stream>>>(cat, catstride, 64, xxb, idxb);
    pq_kernel<<<dim3(32, 16), blk, 0, stream>>>(cat, catstride, 64, w3, P, Q);
    edge2_kernel<<<dim3(256, 16), blk, 0, stream>>>(P, Q, idxb, w4, s3, t3, s4, t4, cat, 64);
    // ---- stage 3 (C=64 on x2) ----
    xx_kernel<<<128, blk, 0, stream>>>(cat + 64 * 2048, catstride, 64, xxb);
    knn_kernel<<<dim3(256, 16), blk512, 0, stream>>>(cat + 64 * 2048, catstride, 64, xxb, idxb);
    pq_kernel<<<dim3(32, 16), blk, 0, stream>>>(cat + 64 * 2048, catstride, 64, w5, P, Q);
    edge1_kernel<<<dim3(512, 16), blk, 0, stream>>>(P, Q, idxb, s5, t5, cat, 128);
    // ---- head ----
    gemm_kernel<<<dim3(16, 16, 16), blk, 0, stream>>>(w6, 192, 192, cat, catstride, s6, t6, nullptr, 1024,
                                                      nullptr, 0, ep);
    gmax_final<<<64, blk, 0, stream>>>(ep, g);
    bias7_kernel<<<dim3(16 * 512), dim3(64), 0, stream>>>(w7, g, b7);
    gemm_kernel<<<dim3(8, 16, 16), blk, 0, stream>>>(w7 + 1024, 1216, 192, cat, catstride, s7, t7, b7, 512,
                                                     h7, (long)512 * 2048, nullptr);
    gemm_kernel<<<dim3(4, 16, 16), blk, 0, stream>>>(w8, 512, 512, h7, (long)512 * 2048, s8, t8, nullptr, 256,
                                                     h8, (long)256 * 2048, nullptr);
    w9_kernel<<<128, blk, 0, stream>>>(w9, h8, (float*)d_out);
}

// Round 3
// 1313.054 us; speedup vs baseline: 2.3971x; 1.1470x over previous
//
#include <hip/hip_runtime.h>
#include <math.h>

#define KNNK 20
#define BEFORE(v1, g1, v2, g2) (((v1) > (v2)) || ((v1) == (v2) && (g1) < (g2)))

__device__ __forceinline__ float lrelu(float v) { return v >= 0.f ? v : 0.2f * v; }

// ---------------- xx[b][n] = sum_c f[b][c][n]^2 ----------------
__global__ __launch_bounds__(256) void xx_kernel(const float* __restrict__ f, long bstride, int C,
                                                 float* __restrict__ xx) {
    int i = blockIdx.x * 256 + threadIdx.x;   // over B*N
    int b = i >> 11, n = i & 2047;
    const float* fb = f + (long)b * bstride;
    float s = 0.f;
    for (int c = 0; c < C; ++c) { float v = fb[c * 2048 + n]; s = fmaf(v, v, s); }
    xx[i] = s;
}

// ---------------- KNN: per 8-row strip, Gram + bitonic top-20 ----------------
// grid (N/8, B), block 512 (8 waves, 1 row per wave). 64 KB LDS -> 2 blocks/CU.
// Selection: per-lane top-3 build, bitonic sort of the 128 (top-2/lane) candidates by
// (value desc, index asc) = exact JAX top_k order; repair loop handles lanes with >=3 winners.
__global__ __launch_bounds__(512, 4) void knn_kernel(const float* __restrict__ f, long bstride, int C,
                                                     const float* __restrict__ xx, int* __restrict__ idx_out) {
    __shared__ __align__(16) float lds[8 * 2048];
    int b = blockIdx.y;
    int n0 = blockIdx.x * 8;
    int t = threadIdx.x;
    const float* fb = f + (long)b * bstride;

    // stage center block A[c][j] = f[c][n0+j]
    for (int e = t; e < C * 8; e += 512) {
        int c = e >> 3, j = e & 7;
        lds[e] = fb[c * 2048 + n0 + j];
    }
    __syncthreads();

    // Gram: thread t owns cols m0..m0+3, all 8 rows (accumulation order = bit-identical to prior rounds)
    float acc[8][4];
#pragma unroll
    for (int i = 0; i < 8; ++i)
#pragma unroll
        for (int j = 0; j < 4; ++j) acc[i][j] = 0.f;
    int m0 = t * 4;
    for (int c = 0; c < C; ++c) {
        float4 b4 = *(const float4*)(fb + c * 2048 + m0);
        float bv[4] = {b4.x, b4.y, b4.z, b4.w};
        float4 a0 = *(const float4*)(lds + c * 8);
        float4 a1 = *(const float4*)(lds + c * 8 + 4);
        float av[8] = {a0.x, a0.y, a0.z, a0.w, a1.x, a1.y, a1.z, a1.w};
#pragma unroll
        for (int i = 0; i < 8; ++i)
#pragma unroll
            for (int j = 0; j < 4; ++j) acc[i][j] = fmaf(av[i], bv[j], acc[i][j]);
    }
    float xn[8];
#pragma unroll
    for (int i = 0; i < 8; ++i) xn[i] = xx[b * 2048 + n0 + i];
    float4 xm4 = *(const float4*)(xx + b * 2048 + m0);
    float xm[4] = {xm4.x, xm4.y, xm4.z, xm4.w};

    __syncthreads();
#pragma unroll
    for (int i = 0; i < 8; ++i) {
        float4 o;
        o.x = (2.f * acc[i][0] - xn[i]) - xm[0];
        o.y = (2.f * acc[i][1] - xn[i]) - xm[1];
        o.z = (2.f * acc[i][2] - xn[i]) - xm[2];
        o.w = (2.f * acc[i][3] - xn[i]) - xm[3];
        *(float4*)(lds + i * 2048 + m0) = o;
    }
    __syncthreads();

    // ---- selection: wave w owns row w ----
    int wave = t >> 6, lane = t & 63;
    const float* srow = lds + wave * 2048;
    float v[32];
#pragma unroll
    for (int j = 0; j < 32; ++j) v[j] = srow[lane + 64 * j];   // global index = lane + 64*j

    // per-lane top-3 (strict '>' keeps earliest index among equals)
    float b1 = -INFINITY, b2 = -INFINITY, b3 = -INFINITY;
    int j1 = 0, j2 = 0, j3 = 0;
#pragma unroll
    for (int j = 0; j < 32; ++j) {
        float vv = v[j];
        bool c1 = vv > b1;
        bool c2 = vv > b2;
        bool c3 = vv > b3;
        b3 = c2 ? b2 : (c3 ? vv : b3);
        j3 = c2 ? j2 : (c3 ? j : j3);
        b2 = c1 ? b1 : (c2 ? vv : b2);
        j2 = c1 ? j1 : (c2 ? j : j2);
        b1 = c1 ? vv : b1;
        j1 = c1 ? j : j1;
    }

    // bitonic sort of 128 candidates: element a = vid lane, element b = vid 64+lane
    float av = b1, bv = b2;
    int ag = lane + (j1 << 6), bg = lane + (j2 << 6);
#pragma unroll
    for (int size = 2; size <= 128; size <<= 1) {
#pragma unroll
        for (int stride = size >> 1; stride >= 1; stride >>= 1) {
            if (stride == 64) {   // in-lane pair (vid lane, vid lane+64); asc=true at size=128
                bool keep = BEFORE(av, ag, bv, bg);
                float tv = keep ? av : bv;
                int tg = keep ? ag : bg;
                bv = keep ? bv : av; bg = keep ? bg : ag;
                av = tv; ag = tg;
            } else {
                float oav = __shfl_xor(av, stride), obv = __shfl_xor(bv, stride);
                int oag = __shfl_xor(ag, stride), obg = __shfl_xor(bg, stride);
                bool low = (lane & stride) == 0;
                bool ascA = (lane & size) == 0;
                bool ascB = (((64 + lane) & size) == 0);
                bool fA = BEFORE(av, ag, oav, oag);
                bool fB = BEFORE(bv, bg, obv, obg);
                bool tA = (low == ascA) ? fA : !fA;
                bool tB = (low == ascB) ? fB : !fB;
                av = tA ? av : oav; ag = tA ? ag : oag;
                bv = tB ? bv : obv; bg = tB ? bg : obg;
            }
        }
    }
    // winners: lanes 0..19 hold ranks 0..19 in (av, ag)

    // repair: a lane whose top-2 are both in the top-20 may owe its 3rd(+) element
    float wv19 = __shfl(av, 19);
    int wg19 = __shfl(ag, 19);
    unsigned used = (1u << j1) | (1u << j2) | (1u << j3);
    float pv = b3;
    int pg = lane + (j3 << 6);
    while (__any(BEFORE(pv, pg, wv19, wg19))) {
        unsigned long long act = __ballot(BEFORE(pv, pg, wv19, wg19));
        int L = __ffsll(act) - 1;
        float cv = __shfl(pv, L);
        int cg2 = __shfl(pg, L);
        unsigned long long cfb = __ballot(lane < 20 && BEFORE(cv, cg2, av, ag));
        int p = 20 - __popcll(cfb);   // insertion position
        float upv = __shfl_up(av, 1);
        int upg = __shfl_up(ag, 1);
        if (lane < 20) {
            if (lane > p) { av = upv; ag = upg; }
            else if (lane == p) { av = cv; ag = cg2; }
        }
        if (lane == L) {   // advance lane L's pending candidate (its next-best unused)
            float nb = -INFINITY;
            int nj = 0;
#pragma unroll
            for (int j = 0; j < 32; ++j) {
                float vvv = ((used >> j) & 1u) ? -INFINITY : v[j];
                if (vvv > nb) { nb = vvv; nj = j; }
            }
            used |= 1u << nj;
            pv = nb;
            pg = lane + (nj << 6);
        }
        wv19 = __shfl(av, 19);
        wg19 = __shfl(ag, 19);
    }
    int* orow = idx_out + ((long)b * 2048 + n0 + wave) * KNNK;
    if (lane < KNNK) orow[lane] = ag;
}

// ---------------- P = Wa @ f, Q = (Wb - Wa) @ f, stored (B, N, 64) n-major ----------------
__global__ __launch_bounds__(256) void pq_kernel(const float* __restrict__ f, long bstride, int C,
                                                 const float* __restrict__ W, float* __restrict__ P,
                                                 float* __restrict__ Q) {
    __shared__ __align__(16) float wa[64 * 64];
    __shared__ __align__(16) float wq[64 * 64];
    __shared__ __align__(16) float X[64 * 64];
    int b = blockIdx.y, n0 = blockIdx.x * 64, t = threadIdx.x;
    const float* fb = f + (long)b * bstride;
    for (int e = t; e < C * 64; e += 256) {
        int k = e >> 6, c = e & 63;
        float a = W[c * 2 * C + k];
        float bv = W[c * 2 * C + C + k];
        wa[k * 64 + c] = a;
        wq[k * 64 + c] = bv - a;
    }
    for (int e = t; e < C * 64; e += 256) {
        int k = e >> 6, j = e & 63;
        X[e] = fb[k * 2048 + n0 + j];
    }
    __syncthreads();
    int cg = t >> 4, ng = t & 15;
    float accP[4][4] = {}, accQ[4][4] = {};
    for (int k = 0; k < C; ++k) {
        float4 a4 = *(const float4*)(wa + k * 64 + cg * 4);
        float4 q4 = *(const float4*)(wq + k * 64 + cg * 4);
        float4 x4 = *(const float4*)(X + k * 64 + ng * 4);
        float av[4] = {a4.x, a4.y, a4.z, a4.w};
        float qv[4] = {q4.x, q4.y, q4.z, q4.w};
        float xv[4] = {x4.x, x4.y, x4.z, x4.w};
#pragma unroll
        for (int i = 0; i < 4; ++i)
#pragma unroll
            for (int j = 0; j < 4; ++j) {
                accP[i][j] = fmaf(av[i], xv[j], accP[i][j]);
                accQ[i][j] = fmaf(qv[i], xv[j], accQ[i][j]);
            }
    }
#pragma unroll
    for (int j = 0; j < 4; ++j) {
        long n = n0 + ng * 4 + j;
        float4 pv = {accP[0][j], accP[1][j], accP[2][j], accP[3][j]};
        float4 qv = {accQ[0][j], accQ[1][j], accQ[2][j], accQ[3][j]};
        *(float4*)(P + ((long)b * 2048 + n) * 64 + cg * 4) = pv;
        *(float4*)(Q + ((long)b * 2048 + n) * 64 + cg * 4) = qv;
    }
}

// ---------------- EdgeConv layer-2 + max over k, fused (stages 1 & 2) ----------------
__global__ __launch_bounds__(256) void edge2_kernel(
    const float* __restrict__ P, const float* __restrict__ Q, const int* __restrict__ idx,
    const float* __restrict__ W2, const float* __restrict__ sa, const float* __restrict__ ta,
    const float* __restrict__ sb, const float* __restrict__ tb, float* __restrict__ out, int cofs) {
    __shared__ __align__(16) float h1[64 * 164];   // [cin][col], padded
    __shared__ __align__(16) float w2l[64 * 64];   // [cin][cout]
    __shared__ int idxl[160];
    int b = blockIdx.y, n0 = blockIdx.x * 8, t = threadIdx.x;
    if (t < 160) idxl[t] = idx[((long)b * 2048 + n0) * KNNK + t];
    for (int e = t; e < 4096; e += 256) { int co = e >> 6, ci = e & 63; w2l[ci * 64 + co] = W2[e]; }
    __syncthreads();
    for (int it = t; it < 2560; it += 256) {   // 160 cols x 16 channel-quads
        int col = it % 160, cg = it / 160;
        int p = col / 20;
        int j = idxl[col];
        int n = n0 + p;
        float4 pv = *(const float4*)(P + ((long)b * 2048 + j) * 64 + cg * 4);
        float4 qv = *(const float4*)(Q + ((long)b * 2048 + n) * 64 + cg * 4);
        float4 sv = *(const float4*)(sa + cg * 4);
        float4 tv = *(const float4*)(ta + cg * 4);
        h1[(cg * 4 + 0) * 164 + col] = lrelu(fmaf(sv.x, pv.x + qv.x, tv.x));
        h1[(cg * 4 + 1) * 164 + col] = lrelu(fmaf(sv.y, pv.y + qv.y, tv.y));
        h1[(cg * 4 + 2) * 164 + col] = lrelu(fmaf(sv.z, pv.z + qv.z, tv.z));
        h1[(cg * 4 + 3) * 164 + col] = lrelu(fmaf(sv.w, pv.w + qv.w, tv.w));
    }
    __syncthreads();
    int p = t & 7, co2 = t >> 3, c0 = co2 * 2;
    float acc0[20], acc1[20];
#pragma unroll
    for (int q = 0; q < 20; ++q) { acc0[q] = 0.f; acc1[q] = 0.f; }
#pragma unroll 4
    for (int k = 0; k < 64; ++k) {
        float2 w = *(const float2*)(w2l + k * 64 + c0);
        const float* hr = h1 + k * 164 + p * 20;
#pragma unroll
        for (int q = 0; q < 5; ++q) {
            float4 h4 = *(const float4*)(hr + q * 4);
            acc0[q * 4 + 0] = fmaf(w.x, h4.x, acc0[q * 4 + 0]);
            acc0[q * 4 + 1] = fmaf(w.x, h4.y, acc0[q * 4 + 1]);
            acc0[q * 4 + 2] = fmaf(w.x, h4.z, acc0[q * 4 + 2]);
            acc0[q * 4 + 3] = fmaf(w.x, h4.w, acc0[q * 4 + 3]);
            acc1[q * 4 + 0] = fmaf(w.y, h4.x, acc1[q * 4 + 0]);
            acc1[q * 4 + 1] = fmaf(w.y, h4.y, acc1[q * 4 + 1]);
            acc1[q * 4 + 2] = fmaf(w.y, h4.z, acc1[q * 4 + 2]);
            acc1[q * 4 + 3] = fmaf(w.y, h4.w, acc1[q * 4 + 3]);
        }
    }
    float s0 = sb[c0], t0v = tb[c0], s1 = sb[c0 + 1], t1v = tb[c0 + 1];
    float m0 = -INFINITY, m1 = -INFINITY;
#pragma unroll
    for (int q = 0; q < 20; ++q) {
        m0 = fmaxf(m0, lrelu(fmaf(s0, acc0[q], t0v)));
        m1 = fmaxf(m1, lrelu(fmaf(s1, acc1[q], t1v)));
    }
    out[(long)b * (192 * 2048) + (long)(cofs + c0) * 2048 + n0 + p] = m0;
    out[(long)b * (192 * 2048) + (long)(cofs + c0 + 1) * 2048 + n0 + p] = m1;
}

// ---------------- Stage 3: gather + affine + lrelu + max over k ----------------
__global__ __launch_bounds__(256) void edge1_kernel(const float* __restrict__ P, const float* __restrict__ Q,
                                                    const int* __restrict__ idx, const float* __restrict__ s,
                                                    const float* __restrict__ tt, float* __restrict__ out,
                                                    int cofs) {
    __shared__ int idxl[80];
    int b = blockIdx.y, n0 = blockIdx.x * 4, t = threadIdx.x;
    int c = t & 63, p = t >> 6;
    if (t < 80) idxl[t] = idx[((long)b * 2048 + n0) * KNNK + t];
    __syncthreads();
    float qv = Q[((long)b * 2048 + n0 + p) * 64 + c];
    float sc = s[c], tc = tt[c];
    float m = -INFINITY;
    for (int kk = 0; kk < KNNK; ++kk) {
        int j = idxl[p * KNNK + kk];
        float v = P[((long)b * 2048 + j) * 64 + c];
        m = fmaxf(m, lrelu(fmaf(sc, v + qv, tc)));
    }
    out[(long)b * (192 * 2048) + (long)(cofs + c) * 2048 + n0 + p] = m;
}

// ---------------- Generic head GEMM ----------------
// thread's 8 columns: nt + ng*4 + {0..3} and nt + 64 + ng*4 + {0..3} (bank-conflict-free xl reads)
__global__ __launch_bounds__(256) void gemm_kernel(
    const float* __restrict__ W, int ldw, int Kdim, const float* __restrict__ X, long xbstride,
    const float* __restrict__ s, const float* __restrict__ tvec, const float* __restrict__ bias, int M,
    float* __restrict__ out, long obstride, float* __restrict__ maxout) {
    __shared__ __align__(16) float wl[32 * 68];
    __shared__ __align__(16) float xl[32 * 132];
    int b = blockIdx.z, ct = blockIdx.x * 64, nt = blockIdx.y * 128, t = threadIdx.x;
    const float* Xb = X + (long)b * xbstride;
    int cg = t >> 4, ng = t & 15;
    float acc[4][8];
#pragma unroll
    for (int i = 0; i < 4; ++i)
#pragma unroll
        for (int j = 0; j < 8; ++j) acc[i][j] = 0.f;
    for (int k0 = 0; k0 < Kdim; k0 += 32) {
        __syncthreads();
        for (int e = t; e < 2048; e += 256) {
            int c = e >> 5, k = e & 31;
            wl[k * 68 + c] = W[(long)(ct + c) * ldw + k0 + k];
        }
        for (int e = t; e < 4096; e += 256) {
            int k = e >> 7, j = e & 127;
            xl[k * 132 + j] = Xb[(long)(k0 + k) * 2048 + nt + j];
        }
        __syncthreads();
#pragma unroll 8
        for (int k = 0; k < 32; ++k) {
            float4 w4 = *(const float4*)(wl + k * 68 + cg * 4);
            float4 xa = *(const float4*)(xl + k * 132 + ng * 4);
            float4 xb = *(const float4*)(xl + k * 132 + 64 + ng * 4);
            float wv[4] = {w4.x, w4.y, w4.z, w4.w};
            float xv[8] = {xa.x, xa.y, xa.z, xa.w, xb.x, xb.y, xb.z, xb.w};
#pragma unroll
            for (int i = 0; i < 4; ++i)
#pragma unroll
                for (int j = 0; j < 8; ++j) acc[i][j] = fmaf(wv[i], xv[j], acc[i][j]);
        }
    }
    if (maxout) {
        __syncthreads();
        float* scr = xl;   // reuse
#pragma unroll
        for (int i = 0; i < 4; ++i) {
            int c = ct + cg * 4 + i;
            float sv = s[c], tv = tvec[c];
            float m = -INFINITY;
#pragma unroll
            for (int j = 0; j < 8; ++j) m = fmaxf(m, lrelu(fmaf(sv, acc[i][j], tv)));
            scr[(cg * 4 + i) * 16 + ng] = m;
        }
        __syncthreads();
        if (t < 64) {
            float m = scr[t * 16];
            for (int j = 1; j < 16; ++j) m = fmaxf(m, scr[t * 16 + j]);
            maxout[((long)b * M + ct + t) * 16 + blockIdx.y] = m;
        }
    } else {
#pragma unroll
        for (int i = 0; i < 4; ++i) {
            int c = ct + cg * 4 + i;
            float bv = bias ? bias[b * M + c] : 0.f;
            float sv = s[c], tv = tvec[c];
            float4 o0, o1;
            o0.x = lrelu(fmaf(sv, acc[i][0] + bv, tv));
            o0.y = lrelu(fmaf(sv, acc[i][1] + bv, tv));
            o0.z = lrelu(fmaf(sv, acc[i][2] + bv, tv));
            o0.w = lrelu(fmaf(sv, acc[i][3] + bv, tv));
            o1.x = lrelu(fmaf(sv, acc[i][4] + bv, tv));
            o1.y = lrelu(fmaf(sv, acc[i][5] + bv, tv));
            o1.z = lrelu(fmaf(sv, acc[i][6] + bv, tv));
            o1.w = lrelu(fmaf(sv, acc[i][7] + bv, tv));
            float* op = out + (long)b * obstride + (long)c * 2048 + nt + ng * 4;
            *(float4*)op = o0;
            *(float4*)(op + 64) = o1;
        }
    }
}

// ---------------- finalize g = max over the 16 n-tile partials ----------------
__global__ __launch_bounds__(256) void gmax_final(const float* __restrict__ ep, float* __restrict__ g) {
    int i = blockIdx.x * 256 + threadIdx.x;   // < 16*1024
    float m = ep[i * 16];
    for (int j = 1; j < 16; ++j) m = fmaxf(m, ep[i * 16 + j]);
    g[i] = m;
}

// ---------------- bias7[b][co] = w7[co, :1024] @ g[b] ----------------
__global__ __launch_bounds__(64) void bias7_kernel(const float* __restrict__ w7, const float* __restrict__ g,
                                                   float* __restrict__ bias7) {
    int o = blockIdx.x;            // b*512 + co
    int b = o >> 9, co = o & 511;
    int lane = threadIdx.x;
    float acc = 0.f;
    for (int j = lane; j < 1024; j += 64) acc = fmaf(w7[(long)co * 1216 + j], g[b * 1024 + j], acc);
#pragma unroll
    for (int off = 32; off >= 1; off >>= 1) acc += __shfl_xor(acc, off);
    if (lane == 0) bias7[o] = acc;
}

// ---------------- y[b][n] = sigmoid(w9 @ h8[:, n]) ----------------
__global__ __launch_bounds__(256) void w9_kernel(const float* __restrict__ w9, const float* __restrict__ h8,
                                                 float* __restrict__ out) {
    int i = blockIdx.x * 256 + threadIdx.x;   // over B*N
    int b = i >> 11, n = i & 2047;
    const float* hb = h8 + (long)b * 256 * 2048 + n;
    float acc = 0.f;
    for (int c = 0; c < 256; ++c) acc = fmaf(w9[c], hb[c * 2048], acc);
    out[i] = 1.f / (1.f + expf(-acc));
}

extern "C" void kernel_launch(void* const* d_in, const int* in_sizes, int n_in,
                              void* d_out, int out_size, void* d_ws, size_t ws_size,
                              hipStream_t stream) {
    (void)in_sizes; (void)n_in; (void)out_size; (void)ws_size;
    const float* x  = (const float*)d_in[0];
    const float* w1 = (const float*)d_in[1];
    const float* w2 = (const float*)d_in[2];
    const float* w3 = (const float*)d_in[3];
    const float* w4 = (const float*)d_in[4];
    const float* w5 = (const float*)d_in[5];
    const float* w6 = (const float*)d_in[6];
    const float* w7 = (const float*)d_in[7];
    const float* w8 = (const float*)d_in[8];
    const float* w9 = (const float*)d_in[9];
    const float* s1 = (const float*)d_in[10]; const float* t1 = (const float*)d_in[11];
    const float* s2 = (const float*)d_in[12]; const float* t2 = (const float*)d_in[13];
    const float* s3 = (const float*)d_in[14]; const float* t3 = (const float*)d_in[15];
    const float* s4 = (const float*)d_in[16]; const float* t4 = (const float*)d_in[17];
    const float* s5 = (const float*)d_in[18]; const float* t5 = (const float*)d_in[19];
    const float* s6 = (const float*)d_in[20]; const float* t6 = (const float*)d_in[21];
    const float* s7 = (const float*)d_in[22]; const float* t7 = (const float*)d_in[23];
    const float* s8 = (const float*)d_in[24]; const float* t8 = (const float*)d_in[25];

    // workspace partition (floats)
    float* cat = (float*)d_ws;                          // 16*192*2048
    float* xxb = cat + (long)16 * 192 * 2048;           // 16*2048
    int*   idxb = (int*)(xxb + 16 * 2048);              // 16*2048*20 ints
    float* P  = (float*)(idxb + (long)16 * 2048 * 20);  // 16*2048*64
    float* Q  = P + (long)16 * 2048 * 64;               // 16*2048*64
    float* ep = Q + (long)16 * 2048 * 64;               // 16*1024*16
    float* g  = ep + 16 * 1024 * 16;                    // 16*1024
    float* b7 = g + 16 * 1024;                          // 16*512
    float* h7 = b7 + 16 * 512;                          // 16*512*2048
    float* h8 = h7 + (long)16 * 512 * 2048;             // 16*256*2048

    dim3 blk(256);
    dim3 blk512(512);
    long catstride = 192 * 2048;

    // ---- stage 1 (C=2) ----
    xx_kernel<<<128, blk, 0, stream>>>(x, 2 * 2048, 2, xxb);
    knn_kernel<<<dim3(256, 16), blk512, 0, stream>>>(x, 2 * 2048, 2, xxb, idxb);
    pq_kernel<<<dim3(32, 16), blk, 0, stream>>>(x, 2 * 2048, 2, w1, P, Q);
    edge2_kernel<<<dim3(256, 16), blk, 0, stream>>>(P, Q, idxb, w2, s1, t1, s2, t2, cat, 0);
    // ---- stage 2 (C=64 on x1) ----
    xx_kernel<<<128, blk, 0, stream>>>(cat, catstride, 64, xxb);
    knn_kernel<<<dim3(256, 16), blk512, 0, stream>>>(cat, catstride, 64, xxb, idxb);
    pq_kernel<<<dim3(32, 16), blk, 0, stream>>>(cat, catstride, 64, w3, P, Q);
    edge2_kernel<<<dim3(256, 16), blk, 0, stream>>>(P, Q, idxb, w4, s3, t3, s4, t4, cat, 64);
    // ---- stage 3 (C=64 on x2) ----
    xx_kernel<<<128, blk, 0, stream>>>(cat + 64 * 2048, catstride, 64, xxb);
    knn_kernel<<<dim3(256, 16), blk512, 0, stream>>>(cat + 64 * 2048, catstride, 64, xxb, idxb);
    pq_kernel<<<dim3(32, 16), blk, 0, stream>>>(cat + 64 * 2048, catstride, 64, w5, P, Q);
    edge1_kernel<<<dim3(512, 16), blk, 0, stream>>>(P, Q, idxb, s5, t5, cat, 128);
    // ---- head ----
    gemm_kernel<<<dim3(16, 16, 16), blk, 0, stream>>>(w6, 192, 192, cat, catstride, s6, t6, nullptr, 1024,
                                                      nullptr, 0, ep);
    gmax_final<<<64, blk, 0, stream>>>(ep, g);
    bias7_kernel<<<dim3(16 * 512), dim3(64), 0, stream>>>(w7, g, b7);
    gemm_kernel<<<dim3(8, 16, 16), blk, 0, stream>>>(w7 + 1024, 1216, 192, cat, catstride, s7, t7, b7, 512,
                                                     h7, (long)512 * 2048, nullptr);
    gemm_kernel<<<dim3(4, 16, 16), blk, 0, stream>>>(w8, 512, 512, h7, (long)512 * 2048, s8, t8, nullptr, 256,
                                                     h8, (long)256 * 2048, nullptr);
    w9_kernel<<<128, blk, 0, stream>>>(w9, h8, (float*)d_out);
}